// Round 2
// baseline (75.480 us; speedup 1.0000x reference)
//
#include <hip/hip_runtime.h>

#define NREG   20
#define EDIM   768
#define DVOL   64
#define HVOL   512
#define WVOL   512
#define HW_    (HVOL * WVOL)
#define DHW_   (DVOL * HVOL * WVOL)
#define NPATCH 16384
#define BTOT   2
#define PROTO_N (NREG * EDIM)            // 15360
#define RF_N    (BTOT * PROTO_N)         // 30720 floats (output 0)
#define TOTAL_PATCHES (BTOT * NPATCH)    // 32768
#define NBUCKET 256                      // 2 batches x 16 zbins x 8 ybins

// workspace layout (u32 words)
#define WS_COUNTS  0                     // 256
#define WS_OFFSETS 256                   // 256
#define WS_KEYS    512                   // 32768
#define WS_PERM    (512 + TOTAL_PATCHES) // 32768

// ---------------------------------------------------------------------------
// Output 0: region_features = prototypes broadcast to (B, 20, 768)
// ---------------------------------------------------------------------------
__global__ __launch_bounds__(256) void proto_copy_kernel(
    const float* __restrict__ proto, float* __restrict__ out)
{
    int i = blockIdx.x * 256 + threadIdx.x;
    if (i < RF_N) out[i] = proto[i % PROTO_N];
}

// ---------------------------------------------------------------------------
// Counting sort of patches by spatial bucket (z/4, y/64) per batch.
// ---------------------------------------------------------------------------
__global__ __launch_bounds__(256) void zero_counts_kernel(unsigned* __restrict__ ws)
{
    ws[WS_COUNTS + threadIdx.x] = 0u;
}

__global__ __launch_bounds__(256) void count_kernel(
    const float* __restrict__ coords, unsigned* __restrict__ ws)
{
    const int patch = blockIdx.x * 256 + threadIdx.x;
    const int b     = patch >> 14;
    const float c0 = coords[patch * 3 + 0] * 64.0f;   // z in [0,64)
    const float c1 = coords[patch * 3 + 1] * 512.0f;  // y in [0,512)
    const int zbin = ((int)c0) >> 2;                  // 0..15
    const int ybin = ((int)c1) >> 6;                  // 0..7
    const unsigned key = (unsigned)(b * 128 + zbin * 8 + ybin);
    ws[WS_KEYS + patch] = key;
    atomicAdd(&ws[WS_COUNTS + key], 1u);
}

__global__ __launch_bounds__(256) void scan_kernel(unsigned* __restrict__ ws)
{
    __shared__ unsigned tmp[NBUCKET];
    const int t = threadIdx.x;
    const unsigned v = ws[WS_COUNTS + t];
    tmp[t] = v;
    __syncthreads();
#pragma unroll
    for (int off = 1; off < NBUCKET; off <<= 1) {
        const unsigned y = (t >= off) ? tmp[t - off] : 0u;
        __syncthreads();
        tmp[t] += y;
        __syncthreads();
    }
    ws[WS_OFFSETS + t] = tmp[t] - v;      // exclusive prefix
}

__global__ __launch_bounds__(256) void scatter_kernel(unsigned* __restrict__ ws)
{
    const int patch = blockIdx.x * 256 + threadIdx.x;
    const unsigned key = ws[WS_KEYS + patch];
    const unsigned rank = atomicAdd(&ws[WS_OFFSETS + key], 1u);
    ws[WS_PERM + rank] = (unsigned)patch;
}

// ---------------------------------------------------------------------------
// Output 1: patch_to_region assignments. One wave per patch (via perm).
// Lane decomposition: xl = lane & 15 (x offset), yh = lane >> 4 (y sub-row).
// 16 iterations cover z in 0..3, y-block in 0..3  -> 1024 voxels / patch.
// Packed 8-bit per-lane histogram (5 regs x 4 regions), butterfly reduce.
// ---------------------------------------------------------------------------
__global__ __launch_bounds__(256) void assign_kernel(
    const int*   __restrict__ seg,
    const float* __restrict__ coords,
    const unsigned* __restrict__ ws,
    float*       __restrict__ out)
{
    __shared__ float smem[4][NREG];

    // XCD-aware swizzle: 8192 blocks, 8 XCDs -> contiguous 1024-block chunks
    const int bid   = (int)blockIdx.x;
    const int sbid  = (bid & 7) * 1024 + (bid >> 3);

    const int lane  = threadIdx.x & 63;
    const int wave  = threadIdx.x >> 6;
    const int patch = (int)ws[WS_PERM + sbid * 4 + wave];
    const int b     = patch >> 14;

    // --- crop box, exactly mirroring the reference float math -------------
    const float c0 = coords[patch * 3 + 0] * 64.0f;   // z
    const float c1 = coords[patch * 3 + 1] * 512.0f;  // y
    const float c2 = coords[patch * 3 + 2] * 512.0f;  // x

    const int sz = (int)fmaxf(0.0f,   floorf(c0 - 2.0f));
    const int ez = (int)fminf(64.0f,  floorf(c0 + 2.0f));
    const int sy = (int)fmaxf(0.0f,   floorf(c1 - 8.0f));
    const int ey = (int)fminf(512.0f, floorf(c1 + 8.0f));
    const int sx = (int)fmaxf(0.0f,   floorf(c2 - 8.0f));
    const int ex = (int)fminf(512.0f, floorf(c2 + 8.0f));

    // --- per-lane constants -------------------------------------------------
    const int xl  = lane & 15;
    const int yh  = lane >> 4;
    const int xi  = sx + xl;
    const int vx  = (xi < ex) ? 1 : 0;
    const int xiC = min(xi, WVOL - 1);
    const int base = b * DHW_;

    // packed 8-bit counters: cc[k] holds regions 4k..4k+3 (0-based region m)
    unsigned int cc[5] = {0u, 0u, 0u, 0u, 0u};

#pragma unroll
    for (int it = 0; it < 16; ++it) {
        const int z  = it >> 2;
        const int yb = it & 3;
        const int zi = sz + z;
        const int yi = sy + yb * 4 + yh;
        const int vz = (zi < ez) ? 1 : 0;
        const int vy = (yi < ey) ? 1 : 0;
        const int ziC = min(zi, DVOL - 1);
        const int yiC = min(yi, HVOL - 1);

        const int val = seg[base + ziC * HW_ + yiC * WVOL + xiC];
        // invalid -> 0 (region ids are 1..20; 0 is never counted)
        const int v = (vz & vy & vx) ? val : 0;

        const int t = v - 1;                       // -1 if not counted
        const unsigned int inc = 1u << ((t & 3) << 3);
        const int q = t >> 2;                      // arithmetic: -1 matches no k
#pragma unroll
        for (int k = 0; k < 5; ++k)
            cc[k] += (q == k) ? inc : 0u;
    }

    // --- unpack 8-bit -> 2x16-bit, butterfly-reduce across 64 lanes --------
    unsigned int lo[5], hi[5];
#pragma unroll
    for (int k = 0; k < 5; ++k) {
        lo[k] = cc[k] & 0x00FF00FFu;          // fields: m=4k (lo16), m=4k+2 (hi16)
        hi[k] = (cc[k] >> 8) & 0x00FF00FFu;   // fields: m=4k+1,       m=4k+3
    }
#pragma unroll
    for (int off = 1; off < 64; off <<= 1) {
#pragma unroll
        for (int k = 0; k < 5; ++k) {
            lo[k] += (unsigned int)__shfl_xor((int)lo[k], off);
            hi[k] += (unsigned int)__shfl_xor((int)hi[k], off);
        }
    }

    // total count over all 20 regions (every lane has the full result)
    unsigned int tot = 0u;
#pragma unroll
    for (int k = 0; k < 5; ++k)
        tot += (lo[k] & 0xFFFFu) + (lo[k] >> 16) + (hi[k] & 0xFFFFu) + (hi[k] >> 16);

    if (lane == 0) {
#pragma unroll
        for (int k = 0; k < 5; ++k) {
            smem[wave][4 * k + 0] = (float)(lo[k] & 0xFFFFu);
            smem[wave][4 * k + 1] = (float)(hi[k] & 0xFFFFu);
            smem[wave][4 * k + 2] = (float)(lo[k] >> 16);
            smem[wave][4 * k + 3] = (float)(hi[k] >> 16);
        }
    }
    __syncthreads();

    // --- normalization -----------------------------------------------------
    const float nz = (float)max(ez - sz, 0);
    const float ny = (float)max(ey - sy, 0);
    const float nx = (float)max(ex - sx, 0);
    const float numel = nz * ny * nx;
    const float denom = fmaxf(numel, 1.0f);
    const float s = (float)tot / denom + (float)NREG * 1e-6f;

    if (lane < NREG) {
        const float cnt = smem[wave][lane];
        const float a = cnt / denom + 1e-6f;
        out[RF_N + patch * NREG + lane] = a / s;
    }
}

// ---------------------------------------------------------------------------
extern "C" void kernel_launch(void* const* d_in, const int* in_sizes, int n_in,
                              void* d_out, int out_size, void* d_ws, size_t ws_size,
                              hipStream_t stream)
{
    const int*   seg    = (const int*)d_in[0];
    const float* coords = (const float*)d_in[1];
    const float* proto  = (const float*)d_in[2];
    float*       out    = (float*)d_out;
    unsigned*    ws     = (unsigned*)d_ws;

    hipLaunchKernelGGL(proto_copy_kernel, dim3(RF_N / 256), dim3(256), 0, stream,
                       proto, out);
    hipLaunchKernelGGL(zero_counts_kernel, dim3(1), dim3(256), 0, stream, ws);
    hipLaunchKernelGGL(count_kernel, dim3(TOTAL_PATCHES / 256), dim3(256), 0, stream,
                       coords, ws);
    hipLaunchKernelGGL(scan_kernel, dim3(1), dim3(NBUCKET), 0, stream, ws);
    hipLaunchKernelGGL(scatter_kernel, dim3(TOTAL_PATCHES / 256), dim3(256), 0, stream,
                       ws);
    hipLaunchKernelGGL(assign_kernel, dim3(TOTAL_PATCHES / 4), dim3(256), 0, stream,
                       seg, coords, ws, out);
}

// Round 3
// 58.716 us; speedup vs baseline: 1.2855x; 1.2855x over previous
//
#include <hip/hip_runtime.h>

#define NREG   20
#define EDIM   768
#define DVOL   64
#define HVOL   512
#define WVOL   512
#define HW_    (HVOL * WVOL)
#define DHW_   (DVOL * HVOL * WVOL)
#define NPATCH 16384
#define BTOT   2
#define PROTO_N (NREG * EDIM)            // 15360
#define RF_N    (BTOT * PROTO_N)         // 30720 floats (output 0)
#define TOTAL_PATCHES (BTOT * NPATCH)    // 32768

// 16-byte load with only 4-byte alignment guarantee (rows start at arbitrary
// int offsets). With gfx950 unaligned-access-mode this emits
// global_load_dwordx4; worst case the compiler splits into dword loads.
struct __attribute__((packed, aligned(4))) int4p { int x, y, z, w; };

// ---------------------------------------------------------------------------
// One wave per patch. Lane = (yy = lane>>2, chunk xl4 = lane&3).
// Each lane loads one int4 (4 x-voxels) per z-slice -> 4 VMEM instr / patch.
// Packed 8-bit per-lane histogram (5 regs x 4 regions), hybrid butterfly.
// Blocks 0..119 additionally copy the prototype broadcast (output 0).
// ---------------------------------------------------------------------------
__global__ __launch_bounds__(256) void assign_kernel(
    const int*   __restrict__ seg,
    const float* __restrict__ coords,
    const float* __restrict__ proto,
    float*       __restrict__ out)
{
    __shared__ float smem[4][NREG];

    // fused output 0: region_features = broadcast prototypes (120 blocks)
    if (blockIdx.x < RF_N / 256) {
        const int i = blockIdx.x * 256 + threadIdx.x;
        out[i] = proto[i >= PROTO_N ? i - PROTO_N : i];
    }

    const int lane  = threadIdx.x & 63;
    const int wave  = threadIdx.x >> 6;
    const int patch = blockIdx.x * 4 + wave;          // grid = 8192 -> exact
    const int b     = patch >> 14;                    // patch / NPATCH

    // --- crop box, exactly mirroring the reference float math --------------
    const float c0 = coords[patch * 3 + 0] * 64.0f;   // z
    const float c1 = coords[patch * 3 + 1] * 512.0f;  // y
    const float c2 = coords[patch * 3 + 2] * 512.0f;  // x

    const int sz = (int)fmaxf(0.0f,   floorf(c0 - 2.0f));
    const int ez = (int)fminf(64.0f,  floorf(c0 + 2.0f));
    const int sy = (int)fmaxf(0.0f,   floorf(c1 - 8.0f));
    const int ey = (int)fminf(512.0f, floorf(c1 + 8.0f));
    const int sx = (int)fmaxf(0.0f,   floorf(c2 - 8.0f));
    const int ex = (int)fminf(512.0f, floorf(c2 + 8.0f));

    // --- per-lane constants ------------------------------------------------
    const int xl4  = lane & 3;                 // which 4-int chunk of the row
    const int yy   = lane >> 2;                // y offset 0..15
    const int p_lo = sx + 4 * xl4;             // intended chunk start
    const int st   = min(p_lo, WVOL - 4);      // clamped load start (in-row)
    const int yi   = sy + yy;
    const int vy   = (yi < ey) ? 1 : 0;
    const int yiC  = min(yi, HVOL - 1);
    const int base = b * DHW_;

    // per-element validity (z-independent part)
    int vm[4];
#pragma unroll
    for (int j = 0; j < 4; ++j) {
        const int pos = st + j;
        vm[j] = (pos >= p_lo && pos < ex && vy) ? 1 : 0;
    }

    // packed 8-bit counters: cc[k] holds regions 4k..4k+3 (0-based region m)
    unsigned int cc[5] = {0u, 0u, 0u, 0u, 0u};

#pragma unroll
    for (int z = 0; z < 4; ++z) {
        const int zi = sz + z;
        if (zi < ez) {                          // wave-uniform branch
            const int ziC = min(zi, DVOL - 1);
            const int4p q4 = *(const int4p*)(seg + base + ziC * HW_ + yiC * WVOL + st);
            const int vals[4] = {q4.x, q4.y, q4.z, q4.w};
#pragma unroll
            for (int j = 0; j < 4; ++j) {
                const int v = vm[j] ? vals[j] : 0;   // 0 never counted
                const int t = v - 1;                 // -1 if not counted
                const unsigned int inc = 1u << ((t & 3) << 3);
                const int q = t >> 2;                // -1 matches no k
#pragma unroll
                for (int k = 0; k < 5; ++k)
                    cc[k] += (q == k) ? inc : 0u;
            }
        }
    }

    // --- butterfly reduce: 3 steps packed 8-bit (max 128/field, no carry) --
#pragma unroll
    for (int off = 1; off < 8; off <<= 1) {
#pragma unroll
        for (int k = 0; k < 5; ++k)
            cc[k] += (unsigned int)__shfl_xor((int)cc[k], off);
    }

    // unpack 8-bit -> 2x16-bit, 3 more steps across lane groups of 8
    unsigned int lo[5], hi[5];
#pragma unroll
    for (int k = 0; k < 5; ++k) {
        lo[k] = cc[k] & 0x00FF00FFu;          // fields: m=4k (lo16), m=4k+2 (hi16)
        hi[k] = (cc[k] >> 8) & 0x00FF00FFu;   // fields: m=4k+1,       m=4k+3
    }
#pragma unroll
    for (int off = 8; off < 64; off <<= 1) {
#pragma unroll
        for (int k = 0; k < 5; ++k) {
            lo[k] += (unsigned int)__shfl_xor((int)lo[k], off);
            hi[k] += (unsigned int)__shfl_xor((int)hi[k], off);
        }
    }

    // total count over all 20 regions (every lane has the full result)
    unsigned int tot = 0u;
#pragma unroll
    for (int k = 0; k < 5; ++k)
        tot += (lo[k] & 0xFFFFu) + (lo[k] >> 16) + (hi[k] & 0xFFFFu) + (hi[k] >> 16);

    if (lane == 0) {
#pragma unroll
        for (int k = 0; k < 5; ++k) {
            smem[wave][4 * k + 0] = (float)(lo[k] & 0xFFFFu);
            smem[wave][4 * k + 1] = (float)(hi[k] & 0xFFFFu);
            smem[wave][4 * k + 2] = (float)(lo[k] >> 16);
            smem[wave][4 * k + 3] = (float)(hi[k] >> 16);
        }
    }
    __syncthreads();

    // --- normalization -----------------------------------------------------
    const float nz = (float)max(ez - sz, 0);
    const float ny = (float)max(ey - sy, 0);
    const float nx = (float)max(ex - sx, 0);
    const float numel = nz * ny * nx;
    const float denom = fmaxf(numel, 1.0f);
    const float s = (float)tot / denom + (float)NREG * 1e-6f;

    if (lane < NREG) {
        const float cnt = smem[wave][lane];
        const float a = cnt / denom + 1e-6f;
        out[RF_N + patch * NREG + lane] = a / s;
    }
}

// ---------------------------------------------------------------------------
extern "C" void kernel_launch(void* const* d_in, const int* in_sizes, int n_in,
                              void* d_out, int out_size, void* d_ws, size_t ws_size,
                              hipStream_t stream)
{
    const int*   seg    = (const int*)d_in[0];
    const float* coords = (const float*)d_in[1];
    const float* proto  = (const float*)d_in[2];
    float*       out    = (float*)d_out;

    hipLaunchKernelGGL(assign_kernel, dim3(TOTAL_PATCHES / 4), dim3(256), 0, stream,
                       seg, coords, proto, out);
}